// Round 1
// baseline (536.341 us; speedup 1.0000x reference)
//
#include <hip/hip_runtime.h>

#define D_MODEL 1024
#define N_HEADS 16
#define DK      64
#define BATCH   4
#define SEQ     2048
#define NROW    (BATCH*SEQ)   // 8192

typedef __attribute__((ext_vector_type(8))) short bf16x8;
typedef __attribute__((ext_vector_type(4))) float f32x4;

__device__ __forceinline__ unsigned short f2bf(float f) {
  unsigned int u = __float_as_uint(f);
  u += 0x7fff + ((u >> 16) & 1);          // round-to-nearest-even
  return (unsigned short)(u >> 16);
}
__device__ __forceinline__ float bf2f(unsigned short h) {
  return __uint_as_float(((unsigned int)h) << 16);
}

__device__ __forceinline__ void gload_lds16(const void* g, void* l) {
  __builtin_amdgcn_global_load_lds((const __attribute__((address_space(1))) void*)g,
                                   (__attribute__((address_space(3))) void*)l,
                                   16, 0, 0);
}

// ---------------- fp32 -> bf16 conversion ----------------
__global__ void cvt_bf16(const float* __restrict__ s, unsigned short* __restrict__ d, int n4) {
  int i = blockIdx.x * 256 + threadIdx.x;
  if (i >= n4) return;
  float4 f = reinterpret_cast<const float4*>(s)[i];
  ushort4 o;
  o.x = f2bf(f.x); o.y = f2bf(f.y); o.z = f2bf(f.z); o.w = f2bf(f.w);
  reinterpret_cast<ushort4*>(d)[i] = o;
}

// ---------------- GEMM: C[m][n] = sum_k A[m][k]*W[n][k] + bias[n] ----------------
// A [M][1024] bf16 row-major, W [1024][1024] bf16 row-major (B^T pattern).
// 128x128 tile, BK=64, 256 threads (4 waves 2x2), each wave 64x64 via 4x4 frags.
template<bool OUT_BF16>
__device__ __forceinline__ void gemm_body(const unsigned short* __restrict__ A,
                                          const unsigned short* __restrict__ Bw,
                                          const float* __restrict__ bias,
                                          unsigned short* __restrict__ Cb,
                                          float* __restrict__ Cf)
{
  __shared__ __align__(16) unsigned short As[128*64];
  __shared__ __align__(16) unsigned short Bs[128*64];
  const int tid  = threadIdx.x;
  const int lane = tid & 63;
  const int w    = tid >> 6;
  const int wr   = w >> 1, wc = w & 1;
  const int m0   = blockIdx.x * 128;
  const int n0   = blockIdx.y * 128;
  const int r    = lane & 15;          // fragment row/col selector
  const int ko   = (lane >> 4) * 8;    // fragment k-offset
  const int srow = lane >> 3;          // staging: 0..7
  const int scol = (lane & 7) * 8;     // staging: 0..56

  f32x4 acc[4][4] = {};

  for (int kt = 0; kt < D_MODEL; kt += 64) {
    __syncthreads();
#pragma unroll
    for (int p = 0; p < 4; ++p) {
      int c = w * 4 + p;               // chunk 0..15 (8 rows each)
      gload_lds16(A  + (size_t)(m0 + c*8 + srow) * D_MODEL + kt + scol, As + c*512);
      gload_lds16(Bw + (size_t)(n0 + c*8 + srow) * D_MODEL + kt + scol, Bs + c*512);
    }
    __syncthreads();                   // drains vmcnt (compiler-emitted)
#pragma unroll
    for (int ks = 0; ks < 2; ++ks) {
      bf16x8 af[4], bfr[4];
#pragma unroll
      for (int m = 0; m < 4; ++m)
        af[m]  = *reinterpret_cast<const bf16x8*>(As + (wr*64 + m*16 + r)*64 + ks*32 + ko);
#pragma unroll
      for (int n = 0; n < 4; ++n)
        bfr[n] = *reinterpret_cast<const bf16x8*>(Bs + (wc*64 + n*16 + r)*64 + ks*32 + ko);
#pragma unroll
      for (int m = 0; m < 4; ++m)
#pragma unroll
        for (int n = 0; n < 4; ++n)
          acc[m][n] = __builtin_amdgcn_mfma_f32_16x16x32_bf16(af[m], bfr[n], acc[m][n], 0, 0, 0);
    }
  }

  const int rq = (lane >> 4) * 4;
#pragma unroll
  for (int m = 0; m < 4; ++m) {
#pragma unroll
    for (int n = 0; n < 4; ++n) {
      int col = n0 + wc*64 + n*16 + r;
      float bv = bias[col];
#pragma unroll
      for (int i = 0; i < 4; ++i) {
        int row = m0 + wr*64 + m*16 + rq + i;
        float v = acc[m][n][i] + bv;
        if (OUT_BF16) Cb[(size_t)row * D_MODEL + col] = f2bf(v);
        else          Cf[(size_t)row * D_MODEL + col] = v;
      }
    }
  }
}

__global__ __launch_bounds__(256)
void gemm_qkv(const unsigned short* __restrict__ xb,
              const unsigned short* __restrict__ Wqb,
              const unsigned short* __restrict__ Wkb,
              const unsigned short* __restrict__ Wvb,
              const float* __restrict__ bq, const float* __restrict__ bk,
              const float* __restrict__ bv,
              unsigned short* __restrict__ Qb, unsigned short* __restrict__ Kb,
              unsigned short* __restrict__ Vb)
{
  const unsigned short* Bw = blockIdx.z == 0 ? Wqb : blockIdx.z == 1 ? Wkb : Wvb;
  const float* bias        = blockIdx.z == 0 ? bq  : blockIdx.z == 1 ? bk  : bv;
  unsigned short* C        = blockIdx.z == 0 ? Qb  : blockIdx.z == 1 ? Kb  : Vb;
  gemm_body<true>(xb, Bw, bias, C, nullptr);
}

__global__ __launch_bounds__(256)
void gemm_out(const unsigned short* __restrict__ Ab,
              const unsigned short* __restrict__ Wob,
              const float* __restrict__ bo, float* __restrict__ Cf)
{
  gemm_body<false>(Ab, Wob, bo, nullptr, Cf);
}

// ---------------- causal flash attention ----------------
// grid: (SEQ/64, BATCH*N_HEADS). 4 waves; wave w owns q-rows w*16..w*16+15.
__global__ __launch_bounds__(256)
void attn_fwd(const unsigned short* __restrict__ Qb,
              const unsigned short* __restrict__ Kb,
              const unsigned short* __restrict__ Vb,
              unsigned short* __restrict__ Ab)
{
  __shared__ __align__(16) unsigned short Ks[64*64];  // [kidx][d]
  __shared__ __align__(16) unsigned short Vt[64*64];  // [d][kidx]
  __shared__ __align__(16) unsigned short Ps[64*64];  // [q_local][kidx], per-wave rows
  const int tid  = threadIdx.x;
  const int lane = tid & 63;
  const int w    = tid >> 6;
  const int qt   = blockIdx.x;
  const int bh   = blockIdx.y;
  const int b    = bh >> 4;
  const int h    = bh & 15;
  const size_t base = (size_t)b * SEQ;
  const int q0   = qt * 64;
  const int r    = lane & 15;
  const int ko   = (lane >> 4) * 8;
  const int rq   = (lane >> 4) * 4;

  // Q fragments in registers (reused across whole KV loop)
  bf16x8 qf[2];
  {
    const unsigned short* qrow = Qb + (base + q0 + w*16 + r) * D_MODEL + h*DK;
    qf[0] = *reinterpret_cast<const bf16x8*>(qrow + ko);
    qf[1] = *reinterpret_cast<const bf16x8*>(qrow + 32 + ko);
  }

  f32x4 acc[4] = {};                           // O accum: 4 d-frags x 4 rows
  float mrun[4] = {-INFINITY, -INFINITY, -INFINITY, -INFINITY};
  float lrun[4] = {};

  for (int t = 0; t <= qt; ++t) {
    __syncthreads();                           // protect Ks/Vt reuse
    // stage K tile (64x64) via global_load_lds, linear layout
#pragma unroll
    for (int p = 0; p < 2; ++p) {
      int c = w*2 + p;                         // chunk 0..7
      gload_lds16(Kb + (base + t*64 + c*8 + (lane>>3)) * D_MODEL + h*DK + (lane&7)*8,
                  Ks + c*512);
    }
    // stage V transposed (reg round-trip; scattered ds_write — v1 simplicity)
#pragma unroll
    for (int p = 0; p < 2; ++p) {
      int idx = tid + p*256;                   // 0..511
      int row = idx >> 3;
      int col = (idx & 7) * 8;
      bf16x8 v = *reinterpret_cast<const bf16x8*>(Vb + (base + t*64 + row) * D_MODEL + h*DK + col);
#pragma unroll
      for (int j = 0; j < 8; ++j)
        Vt[(col + j) * 64 + row] = (unsigned short)v[j];
    }
    __syncthreads();

    // S = Q K^T  (wave's 16 q-rows x 64 k-cols)
    f32x4 sf[4] = {};
#pragma unroll
    for (int f = 0; f < 4; ++f) {
      bf16x8 k0 = *reinterpret_cast<const bf16x8*>(Ks + (f*16 + r)*64 + ko);
      bf16x8 k1 = *reinterpret_cast<const bf16x8*>(Ks + (f*16 + r)*64 + 32 + ko);
      sf[f] = __builtin_amdgcn_mfma_f32_16x16x32_bf16(qf[0], k0, sf[f], 0, 0, 0);
      sf[f] = __builtin_amdgcn_mfma_f32_16x16x32_bf16(qf[1], k1, sf[f], 0, 0, 0);
    }

    // scale + causal mask + row max
    float pmax[4] = {-INFINITY, -INFINITY, -INFINITY, -INFINITY};
    const bool diag = (t == qt);
#pragma unroll
    for (int f = 0; f < 4; ++f)
#pragma unroll
      for (int i = 0; i < 4; ++i) {
        float sv = sf[f][i] * 0.125f;          // 1/sqrt(64)
        if (diag && (t*64 + f*16 + r > q0 + w*16 + rq + i)) sv = -INFINITY;
        sf[f][i] = sv;
        pmax[i] = fmaxf(pmax[i], sv);
      }
#pragma unroll
    for (int d = 1; d < 16; d <<= 1)
#pragma unroll
      for (int i = 0; i < 4; ++i) pmax[i] = fmaxf(pmax[i], __shfl_xor(pmax[i], d));

    // online softmax update
    float fsc[4];
#pragma unroll
    for (int i = 0; i < 4; ++i) {
      float nm = fmaxf(mrun[i], pmax[i]);
      fsc[i] = expf(mrun[i] - nm);             // -inf -> 0 on first tile
      mrun[i] = nm;
    }
    float rsum[4] = {};
#pragma unroll
    for (int f = 0; f < 4; ++f)
#pragma unroll
      for (int i = 0; i < 4; ++i) {
        float p = expf(sf[f][i] - mrun[i]);
        unsigned short pb = f2bf(p);
        Ps[(w*16 + rq + i)*64 + f*16 + r] = pb;
        rsum[i] += bf2f(pb);                   // denominator matches bf16 numerators
      }
    asm volatile("s_waitcnt lgkmcnt(0)" ::: "memory");  // P writes visible to own wave
#pragma unroll
    for (int d = 1; d < 16; d <<= 1)
#pragma unroll
      for (int i = 0; i < 4; ++i) rsum[i] += __shfl_xor(rsum[i], d);
#pragma unroll
    for (int i = 0; i < 4; ++i) lrun[i] = lrun[i] * fsc[i] + rsum[i];
#pragma unroll
    for (int df = 0; df < 4; ++df)
#pragma unroll
      for (int i = 0; i < 4; ++i) acc[df][i] *= fsc[i];

    // O += P V
#pragma unroll
    for (int ks = 0; ks < 2; ++ks) {
      bf16x8 pa = *reinterpret_cast<const bf16x8*>(Ps + (w*16 + r)*64 + ks*32 + ko);
#pragma unroll
      for (int df = 0; df < 4; ++df) {
        bf16x8 vv = *reinterpret_cast<const bf16x8*>(Vt + (df*16 + r)*64 + ks*32 + ko);
        acc[df] = __builtin_amdgcn_mfma_f32_16x16x32_bf16(pa, vv, acc[df], 0, 0, 0);
      }
    }
  }

  // epilogue: O /= l, store bf16
#pragma unroll
  for (int df = 0; df < 4; ++df)
#pragma unroll
    for (int i = 0; i < 4; ++i) {
      float o = acc[df][i] / lrun[i];
      Ab[(base + q0 + w*16 + rq + i) * D_MODEL + h*DK + df*16 + r] = f2bf(o);
    }
}

// ---------------- launch ----------------
extern "C" void kernel_launch(void* const* d_in, const int* in_sizes, int n_in,
                              void* d_out, int out_size, void* d_ws, size_t ws_size,
                              hipStream_t stream) {
  const float* x  = (const float*)d_in[0];
  const float* Wq = (const float*)d_in[1];
  const float* bq = (const float*)d_in[2];
  const float* Wk = (const float*)d_in[3];
  const float* bk = (const float*)d_in[4];
  const float* Wv = (const float*)d_in[5];
  const float* bv = (const float*)d_in[6];
  const float* Wo = (const float*)d_in[7];
  const float* bo = (const float*)d_in[8];

  unsigned short* ws = (unsigned short*)d_ws;
  const size_t NX = (size_t)NROW * D_MODEL;     // 8,388,608
  const size_t NW = (size_t)D_MODEL * D_MODEL;  // 1,048,576
  unsigned short* xb  = ws;                     // [8192][1024] bf16
  unsigned short* Wqb = xb  + NX;
  unsigned short* Wkb = Wqb + NW;
  unsigned short* Wvb = Wkb + NW;
  unsigned short* Wob = Wvb + NW;
  unsigned short* Qb  = Wob + NW;
  unsigned short* Kb  = Qb  + NX;
  unsigned short* Vb  = Kb  + NX;
  unsigned short* Ab  = xb;                     // reuse xb after projections
  // total ws use: (4*NX + 4*NW) * 2 B = 72 MB

  cvt_bf16<<<dim3((unsigned)(NX/4/256)), 256, 0, stream>>>(x,  xb,  (int)(NX/4));
  cvt_bf16<<<dim3((unsigned)(NW/4/256)), 256, 0, stream>>>(Wq, Wqb, (int)(NW/4));
  cvt_bf16<<<dim3((unsigned)(NW/4/256)), 256, 0, stream>>>(Wk, Wkb, (int)(NW/4));
  cvt_bf16<<<dim3((unsigned)(NW/4/256)), 256, 0, stream>>>(Wv, Wvb, (int)(NW/4));
  cvt_bf16<<<dim3((unsigned)(NW/4/256)), 256, 0, stream>>>(Wo, Wob, (int)(NW/4));

  gemm_qkv<<<dim3(NROW/128, D_MODEL/128, 3), 256, 0, stream>>>(
      xb, Wqb, Wkb, Wvb, bq, bk, bv, Qb, Kb, Vb);

  attn_fwd<<<dim3(SEQ/64, BATCH*N_HEADS), 256, 0, stream>>>(Qb, Kb, Vb, Ab);

  gemm_out<<<dim3(NROW/128, D_MODEL/128, 1), 256, 0, stream>>>(
      Ab, Wob, bo, (float*)d_out);
}

// Round 2
// 379.505 us; speedup vs baseline: 1.4133x; 1.4133x over previous
//
#include <hip/hip_runtime.h>

#define D_MODEL 1024
#define N_HEADS 16
#define DK      64
#define BATCH   4
#define SEQ     2048
#define NROW    (BATCH*SEQ)   // 8192

typedef __attribute__((ext_vector_type(8))) short bf16x8;
typedef __attribute__((ext_vector_type(4))) float f32x4;

__device__ __forceinline__ unsigned short f2bf(float f) {
  unsigned int u = __float_as_uint(f);
  u += 0x7fff + ((u >> 16) & 1);          // round-to-nearest-even
  return (unsigned short)(u >> 16);
}
__device__ __forceinline__ float bf2f(unsigned short h) {
  return __uint_as_float(((unsigned int)h) << 16);
}

__device__ __forceinline__ void gload_lds16(const void* g, void* l) {
  __builtin_amdgcn_global_load_lds((const __attribute__((address_space(1))) void*)g,
                                   (__attribute__((address_space(3))) void*)l,
                                   16, 0, 0);
}

// swizzled short-index into a [64-row][64-short] LDS tile: XOR bits 3..5 of col
__device__ __forceinline__ int SW(int row, int col) {
  return row * 64 + (col ^ ((row & 7) << 3));
}

// ---------------- fp32 -> bf16 conversion ----------------
__global__ void cvt_bf16(const float* __restrict__ s, unsigned short* __restrict__ d, int n4) {
  int i = blockIdx.x * 256 + threadIdx.x;
  if (i >= n4) return;
  float4 f = reinterpret_cast<const float4*>(s)[i];
  ushort4 o;
  o.x = f2bf(f.x); o.y = f2bf(f.y); o.z = f2bf(f.z); o.w = f2bf(f.w);
  reinterpret_cast<ushort4*>(d)[i] = o;
}

// ---------------- GEMM: C[m][n] = sum_k A[m][k]*W[n][k] + bias[n] ----------------
// OUT_MODE: 0 = bf16 natural [M][1024]; 1 = f32 natural; 2 = bf16 V-transposed
//           (Vt_g[(b*1024 + col)][2048] <- row s, for attention staging)
template<int OUT_MODE>
__device__ __forceinline__ void gemm_body(const unsigned short* __restrict__ A,
                                          const unsigned short* __restrict__ Bw,
                                          const float* __restrict__ bias,
                                          unsigned short* __restrict__ Cb,
                                          float* __restrict__ Cf)
{
  __shared__ __align__(16) unsigned short As[128*64];
  __shared__ __align__(16) unsigned short Bs[128*64];
  const int tid  = threadIdx.x;
  const int lane = tid & 63;
  const int w    = tid >> 6;
  const int wr   = w >> 1, wc = w & 1;
  const int m0   = blockIdx.x * 128;
  const int n0   = blockIdx.y * 128;
  const int r    = lane & 15;
  const int ko   = (lane >> 4) * 8;
  const int srow = lane >> 3;
  const int scol = (lane & 7) * 8;

  f32x4 acc[4][4] = {};

  for (int kt = 0; kt < D_MODEL; kt += 64) {
    __syncthreads();
#pragma unroll
    for (int p = 0; p < 4; ++p) {
      int c = w * 4 + p;               // chunk 0..15 (8 rows each)
      gload_lds16(A  + (size_t)(m0 + c*8 + srow) * D_MODEL + kt + scol, As + c*512);
      gload_lds16(Bw + (size_t)(n0 + c*8 + srow) * D_MODEL + kt + scol, Bs + c*512);
    }
    __syncthreads();
#pragma unroll
    for (int ks = 0; ks < 2; ++ks) {
      bf16x8 af[4], bfr[4];
#pragma unroll
      for (int m = 0; m < 4; ++m)
        af[m]  = *reinterpret_cast<const bf16x8*>(As + (wr*64 + m*16 + r)*64 + ks*32 + ko);
#pragma unroll
      for (int n = 0; n < 4; ++n)
        bfr[n] = *reinterpret_cast<const bf16x8*>(Bs + (wc*64 + n*16 + r)*64 + ks*32 + ko);
#pragma unroll
      for (int m = 0; m < 4; ++m)
#pragma unroll
        for (int n = 0; n < 4; ++n)
          acc[m][n] = __builtin_amdgcn_mfma_f32_16x16x32_bf16(af[m], bfr[n], acc[m][n], 0, 0, 0);
    }
  }

  const int rq = (lane >> 4) * 4;
#pragma unroll
  for (int m = 0; m < 4; ++m) {
#pragma unroll
    for (int n = 0; n < 4; ++n) {
      int col = n0 + wc*64 + n*16 + r;
      float bv = bias[col];
      int r0 = m0 + wr*64 + m*16 + rq;
      if (OUT_MODE == 2) {
        ushort4 o;
        o.x = f2bf(acc[m][n][0] + bv); o.y = f2bf(acc[m][n][1] + bv);
        o.z = f2bf(acc[m][n][2] + bv); o.w = f2bf(acc[m][n][3] + bv);
        size_t addr = (size_t)((r0 >> 11) * 1024 + col) * SEQ + (r0 & 2047);
        *reinterpret_cast<ushort4*>(Cb + addr) = o;
      } else {
#pragma unroll
        for (int i = 0; i < 4; ++i) {
          float v = acc[m][n][i] + bv;
          if (OUT_MODE == 0) Cb[(size_t)(r0 + i) * D_MODEL + col] = f2bf(v);
          else               Cf[(size_t)(r0 + i) * D_MODEL + col] = v;
        }
      }
    }
  }
}

__global__ __launch_bounds__(256)
void gemm_qkv(const unsigned short* __restrict__ xb,
              const unsigned short* __restrict__ Wqb,
              const unsigned short* __restrict__ Wkb,
              const unsigned short* __restrict__ Wvb,
              const float* __restrict__ bq, const float* __restrict__ bk,
              const float* __restrict__ bv,
              unsigned short* __restrict__ Qb, unsigned short* __restrict__ Kb,
              unsigned short* __restrict__ Vt)
{
  if (blockIdx.z == 0)      gemm_body<0>(xb, Wqb, bq, Qb, nullptr);
  else if (blockIdx.z == 1) gemm_body<0>(xb, Wkb, bk, Kb, nullptr);
  else                      gemm_body<2>(xb, Wvb, bv, Vt, nullptr);
}

__global__ __launch_bounds__(256)
void gemm_out(const unsigned short* __restrict__ Ab,
              const unsigned short* __restrict__ Wob,
              const float* __restrict__ bo, float* __restrict__ Cf)
{
  gemm_body<1>(Ab, Wob, bo, nullptr, Cf);
}

// ---------------- causal flash attention ----------------
// grid: (SEQ/64, BATCH*N_HEADS); qt DESCENDING so long blocks dispatch first.
// 4 waves; wave w owns q-rows w*16..w*16+15. All LDS tiles XOR-swizzled.
__global__ __launch_bounds__(256)
void attn_fwd(const unsigned short* __restrict__ Qb,
              const unsigned short* __restrict__ Kb,
              const unsigned short* __restrict__ Vt,   // [b*1024+h*64+d][2048]
              unsigned short* __restrict__ Ab)
{
  __shared__ __align__(16) unsigned short Ks[64*64];  // [kidx][d] swizzled
  __shared__ __align__(16) unsigned short Vs[64*64];  // [d][kidx] swizzled
  __shared__ __align__(16) unsigned short Ps[64*64];  // [q_local][kidx] swizzled
  const int tid  = threadIdx.x;
  const int lane = tid & 63;
  const int w    = tid >> 6;
  const int qt   = (int)gridDim.x - 1 - (int)blockIdx.x;  // longest first
  const int bh   = blockIdx.y;
  const int b    = bh >> 4;
  const int h    = bh & 15;
  const size_t base = (size_t)b * SEQ;
  const int q0   = qt * 64;
  const int r    = lane & 15;
  const int ko   = (lane >> 4) * 8;
  const int rq   = (lane >> 4) * 4;
  const int xorm = (r & 7) << 3;               // read-side swizzle for row = *+r
  // inverse-swizzled source column (in elements) for gload_lds staging
  const int scol = (((lane & 7) ^ ((lane >> 3) & 7)) << 3);
  const int srow = lane >> 3;                  // 0..7 within chunk

  // log2-domain scaling: S * (1/sqrt(64)) * log2(e)
  const float SC = 0.125f * 1.4426950408889634f;

  bf16x8 qf[2];
  {
    const unsigned short* qrow = Qb + (base + q0 + w*16 + r) * D_MODEL + h*DK;
    qf[0] = *reinterpret_cast<const bf16x8*>(qrow + ko);
    qf[1] = *reinterpret_cast<const bf16x8*>(qrow + 32 + ko);
  }

  f32x4 acc[4] = {};
  float mrun[4] = {-INFINITY, -INFINITY, -INFINITY, -INFINITY};
  float lrun[4] = {};

  for (int t = 0; t <= qt; ++t) {
    __syncthreads();
    // stage K tile [64 kidx][64 d] and V tile [64 d][64 kidx], both swizzled
#pragma unroll
    for (int p = 0; p < 2; ++p) {
      int c = w*2 + p;                         // chunk 0..7 (8 rows each)
      gload_lds16(Kb + (base + t*64 + c*8 + srow) * D_MODEL + h*DK + scol, Ks + c*512);
      gload_lds16(Vt + ((size_t)(b*1024 + h*DK) + c*8 + srow) * SEQ + t*64 + scol, Vs + c*512);
    }
    __syncthreads();

    // S = Q K^T
    f32x4 sf[4] = {};
#pragma unroll
    for (int f = 0; f < 4; ++f) {
      bf16x8 k0 = *reinterpret_cast<const bf16x8*>(Ks + (f*16 + r)*64 + (ko ^ xorm));
      bf16x8 k1 = *reinterpret_cast<const bf16x8*>(Ks + (f*16 + r)*64 + ((32 + ko) ^ xorm));
      sf[f] = __builtin_amdgcn_mfma_f32_16x16x32_bf16(qf[0], k0, sf[f], 0, 0, 0);
      sf[f] = __builtin_amdgcn_mfma_f32_16x16x32_bf16(qf[1], k1, sf[f], 0, 0, 0);
    }

    // scale (log2 domain) + causal mask + row max
    float pmax[4] = {-INFINITY, -INFINITY, -INFINITY, -INFINITY};
    const bool diag = (t == qt);
#pragma unroll
    for (int f = 0; f < 4; ++f)
#pragma unroll
      for (int i = 0; i < 4; ++i) {
        float sv = sf[f][i] * SC;
        if (diag && (t*64 + f*16 + r > q0 + w*16 + rq + i)) sv = -INFINITY;
        sf[f][i] = sv;
        pmax[i] = fmaxf(pmax[i], sv);
      }
#pragma unroll
    for (int d = 1; d < 16; d <<= 1)
#pragma unroll
      for (int i = 0; i < 4; ++i) pmax[i] = fmaxf(pmax[i], __shfl_xor(pmax[i], d));

    float fsc[4];
#pragma unroll
    for (int i = 0; i < 4; ++i) {
      float nm = fmaxf(mrun[i], pmax[i]);
      fsc[i] = exp2f(mrun[i] - nm);            // first tile: exp2(-inf)=0
      mrun[i] = nm;
    }
    float rsum[4] = {};
#pragma unroll
    for (int f = 0; f < 4; ++f)
#pragma unroll
      for (int i = 0; i < 4; ++i) {
        float p = exp2f(sf[f][i] - mrun[i]);
        unsigned short pb = f2bf(p);
        Ps[SW(w*16 + rq + i, f*16 + r)] = pb;
        rsum[i] += bf2f(pb);
      }
#pragma unroll
    for (int d = 1; d < 16; d <<= 1)
#pragma unroll
      for (int i = 0; i < 4; ++i) rsum[i] += __shfl_xor(rsum[i], d);
#pragma unroll
    for (int i = 0; i < 4; ++i) lrun[i] = lrun[i] * fsc[i] + rsum[i];
#pragma unroll
    for (int df = 0; df < 4; ++df)
#pragma unroll
      for (int i = 0; i < 4; ++i) acc[df][i] *= fsc[i];

    // O += P V   (Ps rows are wave-private; compiler orders same-address LDS ops)
#pragma unroll
    for (int ks = 0; ks < 2; ++ks) {
      bf16x8 pa = *reinterpret_cast<const bf16x8*>(Ps + (w*16 + r)*64 + ((ks*32 + ko) ^ xorm));
#pragma unroll
      for (int df = 0; df < 4; ++df) {
        bf16x8 vv = *reinterpret_cast<const bf16x8*>(Vs + (df*16 + r)*64 + ((ks*32 + ko) ^ xorm));
        acc[df] = __builtin_amdgcn_mfma_f32_16x16x32_bf16(pa, vv, acc[df], 0, 0, 0);
      }
    }
  }

  // epilogue: O /= l, store bf16
#pragma unroll
  for (int df = 0; df < 4; ++df)
#pragma unroll
    for (int i = 0; i < 4; ++i) {
      float o = acc[df][i] / lrun[i];
      Ab[(base + q0 + w*16 + rq + i) * D_MODEL + h*DK + df*16 + r] = f2bf(o);
    }
}

// ---------------- launch ----------------
extern "C" void kernel_launch(void* const* d_in, const int* in_sizes, int n_in,
                              void* d_out, int out_size, void* d_ws, size_t ws_size,
                              hipStream_t stream) {
  const float* x  = (const float*)d_in[0];
  const float* Wq = (const float*)d_in[1];
  const float* bq = (const float*)d_in[2];
  const float* Wk = (const float*)d_in[3];
  const float* bk = (const float*)d_in[4];
  const float* Wv = (const float*)d_in[5];
  const float* bv = (const float*)d_in[6];
  const float* Wo = (const float*)d_in[7];
  const float* bo = (const float*)d_in[8];

  unsigned short* ws = (unsigned short*)d_ws;
  const size_t NX = (size_t)NROW * D_MODEL;
  const size_t NW = (size_t)D_MODEL * D_MODEL;
  unsigned short* xb  = ws;
  unsigned short* Wqb = xb  + NX;
  unsigned short* Wkb = Wqb + NW;
  unsigned short* Wvb = Wkb + NW;
  unsigned short* Wob = Wvb + NW;
  unsigned short* Qb  = Wob + NW;
  unsigned short* Kb  = Qb  + NX;
  unsigned short* Vt  = Kb  + NX;   // [b*1024 + h*64 + d][2048]
  unsigned short* Ab  = xb;         // reuse xb after projections

  cvt_bf16<<<dim3((unsigned)(NX/4/256)), 256, 0, stream>>>(x,  xb,  (int)(NX/4));
  cvt_bf16<<<dim3((unsigned)(NW/4/256)), 256, 0, stream>>>(Wq, Wqb, (int)(NW/4));
  cvt_bf16<<<dim3((unsigned)(NW/4/256)), 256, 0, stream>>>(Wk, Wkb, (int)(NW/4));
  cvt_bf16<<<dim3((unsigned)(NW/4/256)), 256, 0, stream>>>(Wv, Wvb, (int)(NW/4));
  cvt_bf16<<<dim3((unsigned)(NW/4/256)), 256, 0, stream>>>(Wo, Wob, (int)(NW/4));

  gemm_qkv<<<dim3(NROW/128, D_MODEL/128, 3), 256, 0, stream>>>(
      xb, Wqb, Wkb, Wvb, bq, bk, bv, Qb, Kb, Vt);

  attn_fwd<<<dim3(SEQ/64, BATCH*N_HEADS), 256, 0, stream>>>(Qb, Kb, Vt, Ab);

  gemm_out<<<dim3(NROW/128, D_MODEL/128, 1), 256, 0, stream>>>(
      Ab, Wob, bo, (float*)d_out);
}

// Round 3
// 328.735 us; speedup vs baseline: 1.6315x; 1.1544x over previous
//
#include <hip/hip_runtime.h>
#include <hip/hip_bf16.h>

#define D_MODEL 1024
#define N_HEADS 16
#define DK      64
#define BATCH   4
#define SEQ     2048
#define NROW    (BATCH*SEQ)   // 8192

typedef __attribute__((ext_vector_type(8))) short bf16x8;
typedef __attribute__((ext_vector_type(4))) float f32x4;

__device__ __forceinline__ unsigned short f2bf(float f) {
  unsigned int u = __float_as_uint(f);
  u += 0x7fff + ((u >> 16) & 1);          // round-to-nearest-even
  return (unsigned short)(u >> 16);
}
__device__ __forceinline__ unsigned short f2bf_hw(float f) {
  __hip_bfloat16 h = __float2bfloat16(f);
  return *reinterpret_cast<unsigned short*>(&h);
}

__device__ __forceinline__ void gload_lds16(const void* g, void* l) {
  __builtin_amdgcn_global_load_lds((const __attribute__((address_space(1))) void*)g,
                                   (__attribute__((address_space(3))) void*)l,
                                   16, 0, 0);
}

// swizzled short-index into a [rows][64-short] LDS tile: XOR bits 3..5 of col
__device__ __forceinline__ int SW(int row, int col) {
  return row * 64 + (col ^ ((row & 7) << 3));
}

// ---------------- fp32 -> bf16 conversion ----------------
__global__ void cvt_bf16(const float* __restrict__ s, unsigned short* __restrict__ d, int n4) {
  int i = blockIdx.x * 256 + threadIdx.x;
  if (i >= n4) return;
  float4 f = reinterpret_cast<const float4*>(s)[i];
  ushort4 o;
  o.x = f2bf(f.x); o.y = f2bf(f.y); o.z = f2bf(f.z); o.w = f2bf(f.w);
  reinterpret_cast<ushort4*>(d)[i] = o;
}

// 4 weight matrices in one launch (z = which)
__global__ void cvt_bf16_w4(const float* __restrict__ s0, const float* __restrict__ s1,
                            const float* __restrict__ s2, const float* __restrict__ s3,
                            unsigned short* __restrict__ d0, unsigned short* __restrict__ d1,
                            unsigned short* __restrict__ d2, unsigned short* __restrict__ d3,
                            int n4) {
  int i = blockIdx.x * 256 + threadIdx.x;
  if (i >= n4) return;
  const float* s = blockIdx.z == 0 ? s0 : blockIdx.z == 1 ? s1 : blockIdx.z == 2 ? s2 : s3;
  unsigned short* d = blockIdx.z == 0 ? d0 : blockIdx.z == 1 ? d1 : blockIdx.z == 2 ? d2 : d3;
  float4 f = reinterpret_cast<const float4*>(s)[i];
  ushort4 o;
  o.x = f2bf(f.x); o.y = f2bf(f.y); o.z = f2bf(f.z); o.w = f2bf(f.w);
  reinterpret_cast<ushort4*>(d)[i] = o;
}

// ---------------- GEMM: C[m][n] = (sum_k A[m][k]*W[n][k] + bias[n]) * scale --------
// OUT_MODE: 0 = bf16 natural [M][1024]; 1 = f32 natural; 2 = bf16 V-transposed
template<int OUT_MODE>
__device__ __forceinline__ void gemm_body(const unsigned short* __restrict__ A,
                                          const unsigned short* __restrict__ Bw,
                                          const float* __restrict__ bias,
                                          unsigned short* __restrict__ Cb,
                                          float* __restrict__ Cf, float scale)
{
  __shared__ __align__(16) unsigned short As[128*64];
  __shared__ __align__(16) unsigned short Bs[128*64];
  const int tid  = threadIdx.x;
  const int lane = tid & 63;
  const int w    = tid >> 6;
  const int wr   = w >> 1, wc = w & 1;
  const int m0   = blockIdx.x * 128;
  const int n0   = blockIdx.y * 128;
  const int r    = lane & 15;
  const int ko   = (lane >> 4) * 8;
  const int srow = lane >> 3;
  const int scol = (lane & 7) * 8;

  f32x4 acc[4][4] = {};

  for (int kt = 0; kt < D_MODEL; kt += 64) {
    __syncthreads();
#pragma unroll
    for (int p = 0; p < 4; ++p) {
      int c = w * 4 + p;
      gload_lds16(A  + (size_t)(m0 + c*8 + srow) * D_MODEL + kt + scol, As + c*512);
      gload_lds16(Bw + (size_t)(n0 + c*8 + srow) * D_MODEL + kt + scol, Bs + c*512);
    }
    __syncthreads();
#pragma unroll
    for (int ks = 0; ks < 2; ++ks) {
      bf16x8 af[4], bfr[4];
#pragma unroll
      for (int m = 0; m < 4; ++m)
        af[m]  = *reinterpret_cast<const bf16x8*>(As + (wr*64 + m*16 + r)*64 + ks*32 + ko);
#pragma unroll
      for (int n = 0; n < 4; ++n)
        bfr[n] = *reinterpret_cast<const bf16x8*>(Bs + (wc*64 + n*16 + r)*64 + ks*32 + ko);
#pragma unroll
      for (int m = 0; m < 4; ++m)
#pragma unroll
        for (int n = 0; n < 4; ++n)
          acc[m][n] = __builtin_amdgcn_mfma_f32_16x16x32_bf16(af[m], bfr[n], acc[m][n], 0, 0, 0);
    }
  }

  const int rq = (lane >> 4) * 4;
#pragma unroll
  for (int m = 0; m < 4; ++m) {
#pragma unroll
    for (int n = 0; n < 4; ++n) {
      int col = n0 + wc*64 + n*16 + r;
      float bv = bias[col];
      int r0 = m0 + wr*64 + m*16 + rq;
      if (OUT_MODE == 2) {
        ushort4 o;
        o.x = f2bf(acc[m][n][0] + bv); o.y = f2bf(acc[m][n][1] + bv);
        o.z = f2bf(acc[m][n][2] + bv); o.w = f2bf(acc[m][n][3] + bv);
        size_t addr = (size_t)((r0 >> 11) * 1024 + col) * SEQ + (r0 & 2047);
        *reinterpret_cast<ushort4*>(Cb + addr) = o;
      } else {
#pragma unroll
        for (int i = 0; i < 4; ++i) {
          float v = (acc[m][n][i] + bv) * scale;
          if (OUT_MODE == 0) Cb[(size_t)(r0 + i) * D_MODEL + col] = f2bf(v);
          else               Cf[(size_t)(r0 + i) * D_MODEL + col] = v;
        }
      }
    }
  }
}

// S*(1/sqrt(64))*log2(e) folded into Q
#define QSCALE (0.125f * 1.4426950408889634f)

__global__ __launch_bounds__(256)
void gemm_qkv(const unsigned short* __restrict__ xb,
              const unsigned short* __restrict__ Wqb,
              const unsigned short* __restrict__ Wkb,
              const unsigned short* __restrict__ Wvb,
              const float* __restrict__ bq, const float* __restrict__ bk,
              const float* __restrict__ bv,
              unsigned short* __restrict__ Qb, unsigned short* __restrict__ Kb,
              unsigned short* __restrict__ Vt)
{
  if (blockIdx.z == 0)      gemm_body<0>(xb, Wqb, bq, Qb, nullptr, QSCALE);
  else if (blockIdx.z == 1) gemm_body<0>(xb, Wkb, bk, Kb, nullptr, 1.0f);
  else                      gemm_body<2>(xb, Wvb, bv, Vt, nullptr, 1.0f);
}

__global__ __launch_bounds__(256)
void gemm_out(const unsigned short* __restrict__ Ab,
              const unsigned short* __restrict__ Wob,
              const float* __restrict__ bo, float* __restrict__ Cf)
{
  gemm_body<1>(Ab, Wob, bo, nullptr, Cf, 1.0f);
}

// ---------------- causal flash attention ----------------
// grid (16, 64), qt descending. QBLK=128 (4 waves x 32 q-rows), KVBLK=64.
// Double-buffered K/V staging, prefetch-before-compute, 1 barrier/iter.
__global__ __launch_bounds__(256)
void attn_fwd(const unsigned short* __restrict__ Qb,
              const unsigned short* __restrict__ Kb,
              const unsigned short* __restrict__ Vt,   // [b*1024+h*64+d][2048]
              unsigned short* __restrict__ Ab)
{
  __shared__ __align__(16) unsigned short Ks[2][64*64];
  __shared__ __align__(16) unsigned short Vs[2][64*64];
  __shared__ __align__(16) unsigned short Ps[128*64];
  const int tid  = threadIdx.x;
  const int lane = tid & 63;
  const int w    = tid >> 6;
  const int qt   = (int)gridDim.x - 1 - (int)blockIdx.x;  // longest first
  const int bh   = blockIdx.y;
  const int b    = bh >> 4;
  const int h    = bh & 15;
  const size_t base = (size_t)b * SEQ;
  const int q0   = qt * 128;
  const int r    = lane & 15;
  const int ko   = (lane >> 4) * 8;
  const int rq   = (lane >> 4) * 4;
  const int xorm = (r & 7) << 3;
  const int scol = (((lane & 7) ^ ((lane >> 3) & 7)) << 3);  // inverse-swz source col
  const int srow = lane >> 3;
  const int aw   = q0 + w*32;              // wave's first global q-row
  const int nt   = (q0 + 127) >> 6;        // last KV tile = 2qt+1

  // Q in registers: 2 row-frags x 2 k-chunks (pre-scaled by QSCALE in GEMM)
  bf16x8 qf[2][2];
#pragma unroll
  for (int m = 0; m < 2; ++m) {
    const unsigned short* qrow = Qb + (base + aw + m*16 + r) * D_MODEL + h*DK;
    qf[m][0] = *reinterpret_cast<const bf16x8*>(qrow + ko);
    qf[m][1] = *reinterpret_cast<const bf16x8*>(qrow + 32 + ko);
  }

  f32x4 acc[2][4] = {};
  float mrun[2][4], lrun[2][4];
#pragma unroll
  for (int m = 0; m < 2; ++m)
#pragma unroll
    for (int i = 0; i < 4; ++i) { mrun[m][i] = -INFINITY; lrun[m][i] = 0.f; }

  // stage tile t into buffer buf
  auto STAGE = [&](int buf, int t) {
#pragma unroll
    for (int p = 0; p < 2; ++p) {
      int c = w*2 + p;                     // chunk 0..7 (8 rows each)
      gload_lds16(Kb + (base + t*64 + c*8 + srow) * D_MODEL + h*DK + scol, &Ks[buf][c*512]);
      gload_lds16(Vt + ((size_t)(b*1024 + h*DK) + c*8 + srow) * SEQ + t*64 + scol, &Vs[buf][c*512]);
    }
  };

  STAGE(0, 0);
  __syncthreads();                         // drains vmcnt for tile 0

  for (int t = 0; t <= nt; ++t) {
    const int cur = t & 1;
    if (t < nt) STAGE(cur ^ 1, t + 1);     // prefetch next tile (overlaps compute)

    const bool dead = (t << 6) > aw + 31;  // tile fully above diagonal for this wave
    if (!dead) {
      // ---- S = Q K^T ----
      f32x4 sf[2][4] = {};
      __builtin_amdgcn_s_setprio(1);
#pragma unroll
      for (int f = 0; f < 4; ++f) {
        bf16x8 k0 = *reinterpret_cast<const bf16x8*>(&Ks[cur][(f*16 + r)*64 + (ko ^ xorm)]);
        bf16x8 k1 = *reinterpret_cast<const bf16x8*>(&Ks[cur][(f*16 + r)*64 + ((32 + ko) ^ xorm)]);
#pragma unroll
        for (int m = 0; m < 2; ++m) {
          sf[m][f] = __builtin_amdgcn_mfma_f32_16x16x32_bf16(qf[m][0], k0, sf[m][f], 0, 0, 0);
          sf[m][f] = __builtin_amdgcn_mfma_f32_16x16x32_bf16(qf[m][1], k1, sf[m][f], 0, 0, 0);
        }
      }
      __builtin_amdgcn_s_setprio(0);

      // ---- causal mask (only the wave's diagonal-overlap tile) ----
      if ((t << 6) + 63 > aw) {
#pragma unroll
        for (int m = 0; m < 2; ++m)
#pragma unroll
          for (int f = 0; f < 4; ++f)
#pragma unroll
            for (int i = 0; i < 4; ++i)
              if (t*64 + f*16 + r > aw + m*16 + rq + i) sf[m][f][i] = -INFINITY;
      }

      // ---- row max (local + 16-lane reduce) ----
      float pmax[2][4];
#pragma unroll
      for (int m = 0; m < 2; ++m)
#pragma unroll
        for (int i = 0; i < 4; ++i)
          pmax[m][i] = fmaxf(fmaxf(sf[m][0][i], sf[m][1][i]),
                             fmaxf(sf[m][2][i], sf[m][3][i]));
#pragma unroll
      for (int d = 1; d < 16; d <<= 1)
#pragma unroll
        for (int m = 0; m < 2; ++m)
#pragma unroll
          for (int i = 0; i < 4; ++i)
            pmax[m][i] = fmaxf(pmax[m][i], __shfl_xor(pmax[m][i], d));

      // ---- defer-max (T13): rescale only when max grows by > 8 (log2 units) ----
      bool need = false;
#pragma unroll
      for (int m = 0; m < 2; ++m)
#pragma unroll
        for (int i = 0; i < 4; ++i)
          need |= (pmax[m][i] > mrun[m][i] + 8.0f);
      if (__any(need)) {
#pragma unroll
        for (int m = 0; m < 2; ++m)
#pragma unroll
          for (int i = 0; i < 4; ++i) {
            float nm = fmaxf(mrun[m][i], pmax[m][i]);
            float fs = exp2f(mrun[m][i] - nm);
            mrun[m][i] = nm;
            lrun[m][i] *= fs;
#pragma unroll
            for (int df = 0; df < 4; ++df) acc[m][df][i] *= fs;
          }
      }

      // ---- P = exp2(S - m), store bf16 to Ps, per-lane partial sums ----
#pragma unroll
      for (int m = 0; m < 2; ++m)
#pragma unroll
        for (int f = 0; f < 4; ++f)
#pragma unroll
          for (int i = 0; i < 4; ++i) {
            float p = exp2f(sf[m][f][i] - mrun[m][i]);
            lrun[m][i] += p;
            Ps[SW(w*32 + m*16 + rq + i, f*16 + r)] = f2bf_hw(p);
          }

      // ---- O += P V ----
      __builtin_amdgcn_s_setprio(1);
#pragma unroll
      for (int ks = 0; ks < 2; ++ks) {
        bf16x8 pa[2];
#pragma unroll
        for (int m = 0; m < 2; ++m)
          pa[m] = *reinterpret_cast<const bf16x8*>(&Ps[(w*32 + m*16 + r)*64 + ((ks*32 + ko) ^ xorm)]);
#pragma unroll
        for (int df = 0; df < 4; ++df) {
          bf16x8 vv = *reinterpret_cast<const bf16x8*>(&Vs[cur][(df*16 + r)*64 + ((ks*32 + ko) ^ xorm)]);
#pragma unroll
          for (int m = 0; m < 2; ++m)
            acc[m][df] = __builtin_amdgcn_mfma_f32_16x16x32_bf16(pa[m], vv, acc[m][df], 0, 0, 0);
        }
      }
      __builtin_amdgcn_s_setprio(0);
    }
    __syncthreads();                       // one barrier per tile
  }

  // ---- epilogue: reduce lrun across 16 lanes, normalize, store ----
#pragma unroll
  for (int d = 1; d < 16; d <<= 1)
#pragma unroll
    for (int m = 0; m < 2; ++m)
#pragma unroll
      for (int i = 0; i < 4; ++i)
        lrun[m][i] += __shfl_xor(lrun[m][i], d);

#pragma unroll
  for (int m = 0; m < 2; ++m)
#pragma unroll
    for (int df = 0; df < 4; ++df)
#pragma unroll
      for (int i = 0; i < 4; ++i) {
        float o = acc[m][df][i] / lrun[m][i];
        Ab[(base + aw + m*16 + rq + i) * D_MODEL + h*DK + df*16 + r] = f2bf(o);
      }
}

// ---------------- launch ----------------
extern "C" void kernel_launch(void* const* d_in, const int* in_sizes, int n_in,
                              void* d_out, int out_size, void* d_ws, size_t ws_size,
                              hipStream_t stream) {
  const float* x  = (const float*)d_in[0];
  const float* Wq = (const float*)d_in[1];
  const float* bq = (const float*)d_in[2];
  const float* Wk = (const float*)d_in[3];
  const float* bk = (const float*)d_in[4];
  const float* Wv = (const float*)d_in[5];
  const float* bv = (const float*)d_in[6];
  const float* Wo = (const float*)d_in[7];
  const float* bo = (const float*)d_in[8];

  unsigned short* ws = (unsigned short*)d_ws;
  const size_t NX = (size_t)NROW * D_MODEL;
  const size_t NW = (size_t)D_MODEL * D_MODEL;
  unsigned short* xb  = ws;
  unsigned short* Wqb = xb  + NX;
  unsigned short* Wkb = Wqb + NW;
  unsigned short* Wvb = Wkb + NW;
  unsigned short* Wob = Wvb + NW;
  unsigned short* Qb  = Wob + NW;
  unsigned short* Kb  = Qb  + NX;
  unsigned short* Vt  = Kb  + NX;   // [b*1024 + h*64 + d][2048]
  unsigned short* Ab  = xb;         // reuse xb after projections

  cvt_bf16<<<dim3((unsigned)(NX/4/256)), 256, 0, stream>>>(x, xb, (int)(NX/4));
  cvt_bf16_w4<<<dim3((unsigned)(NW/4/256), 1, 4), 256, 0, stream>>>(
      Wq, Wk, Wv, Wo, Wqb, Wkb, Wvb, Wob, (int)(NW/4));

  gemm_qkv<<<dim3(NROW/128, D_MODEL/128, 3), 256, 0, stream>>>(
      xb, Wqb, Wkb, Wvb, bq, bk, bv, Qb, Kb, Vt);

  attn_fwd<<<dim3(SEQ/128, BATCH*N_HEADS), 256, 0, stream>>>(Qb, Kb, Vt, Ab);

  gemm_out<<<dim3(NROW/128, D_MODEL/128, 1), 256, 0, stream>>>(
      Ab, Wob, bo, (float*)d_out);
}

// Round 4
// 243.050 us; speedup vs baseline: 2.2067x; 1.3525x over previous
//
#include <hip/hip_runtime.h>
#include <hip/hip_bf16.h>

#define D_MODEL 1024
#define N_HEADS 16
#define DK      64
#define BATCH   4
#define SEQ     2048
#define NROW    (BATCH*SEQ)   // 8192

typedef __attribute__((ext_vector_type(8)))  short bf16x8;
typedef __attribute__((ext_vector_type(4)))  float f32x4;
typedef __attribute__((ext_vector_type(16))) float f32x16;
typedef __attribute__((ext_vector_type(4)))  unsigned int u32x4;

__device__ __forceinline__ unsigned short f2bf(float f) {
  unsigned int u = __float_as_uint(f);
  u += 0x7fff + ((u >> 16) & 1);          // round-to-nearest-even
  return (unsigned short)(u >> 16);
}

__device__ __forceinline__ void gload_lds16(const void* g, void* l) {
  __builtin_amdgcn_global_load_lds((const __attribute__((address_space(1))) void*)g,
                                   (__attribute__((address_space(3))) void*)l,
                                   16, 0, 0);
}

// ---------------- fp32 -> bf16 conversion ----------------
__global__ void cvt_bf16(const float* __restrict__ s, unsigned short* __restrict__ d, int n4) {
  int i = blockIdx.x * 256 + threadIdx.x;
  if (i >= n4) return;
  float4 f = reinterpret_cast<const float4*>(s)[i];
  ushort4 o;
  o.x = f2bf(f.x); o.y = f2bf(f.y); o.z = f2bf(f.z); o.w = f2bf(f.w);
  reinterpret_cast<ushort4*>(d)[i] = o;
}

__global__ void cvt_bf16_w4(const float* __restrict__ s0, const float* __restrict__ s1,
                            const float* __restrict__ s2, const float* __restrict__ s3,
                            unsigned short* __restrict__ d0, unsigned short* __restrict__ d1,
                            unsigned short* __restrict__ d2, unsigned short* __restrict__ d3,
                            int n4) {
  int i = blockIdx.x * 256 + threadIdx.x;
  if (i >= n4) return;
  const float* s = blockIdx.z == 0 ? s0 : blockIdx.z == 1 ? s1 : blockIdx.z == 2 ? s2 : s3;
  unsigned short* d = blockIdx.z == 0 ? d0 : blockIdx.z == 1 ? d1 : blockIdx.z == 2 ? d2 : d3;
  float4 f = reinterpret_cast<const float4*>(s)[i];
  ushort4 o;
  o.x = f2bf(f.x); o.y = f2bf(f.y); o.z = f2bf(f.z); o.w = f2bf(f.w);
  reinterpret_cast<ushort4*>(d)[i] = o;
}

// ---------------- GEMM: C[m][n] = (sum_k A[m][k]*W[n][k] + bias[n]) * scale --------
template<int OUT_MODE>   // 0 = bf16 natural; 1 = f32 natural; 2 = bf16 V-transposed
__device__ __forceinline__ void gemm_body(const unsigned short* __restrict__ A,
                                          const unsigned short* __restrict__ Bw,
                                          const float* __restrict__ bias,
                                          unsigned short* __restrict__ Cb,
                                          float* __restrict__ Cf, float scale)
{
  __shared__ __align__(16) unsigned short As[128*64];
  __shared__ __align__(16) unsigned short Bs[128*64];
  const int tid  = threadIdx.x;
  const int lane = tid & 63;
  const int w    = tid >> 6;
  const int wr   = w >> 1, wc = w & 1;
  const int m0   = blockIdx.x * 128;
  const int n0   = blockIdx.y * 128;
  const int r    = lane & 15;
  const int ko   = (lane >> 4) * 8;
  const int srow = lane >> 3;
  const int scol = (lane & 7) * 8;

  f32x4 acc[4][4] = {};

  for (int kt = 0; kt < D_MODEL; kt += 64) {
    __syncthreads();
#pragma unroll
    for (int p = 0; p < 4; ++p) {
      int c = w * 4 + p;
      gload_lds16(A  + (size_t)(m0 + c*8 + srow) * D_MODEL + kt + scol, As + c*512);
      gload_lds16(Bw + (size_t)(n0 + c*8 + srow) * D_MODEL + kt + scol, Bs + c*512);
    }
    __syncthreads();
#pragma unroll
    for (int ks = 0; ks < 2; ++ks) {
      bf16x8 af[4], bfr[4];
#pragma unroll
      for (int m = 0; m < 4; ++m)
        af[m]  = *reinterpret_cast<const bf16x8*>(As + (wr*64 + m*16 + r)*64 + ks*32 + ko);
#pragma unroll
      for (int n = 0; n < 4; ++n)
        bfr[n] = *reinterpret_cast<const bf16x8*>(Bs + (wc*64 + n*16 + r)*64 + ks*32 + ko);
#pragma unroll
      for (int m = 0; m < 4; ++m)
#pragma unroll
        for (int n = 0; n < 4; ++n)
          acc[m][n] = __builtin_amdgcn_mfma_f32_16x16x32_bf16(af[m], bfr[n], acc[m][n], 0, 0, 0);
    }
  }

  const int rq = (lane >> 4) * 4;
#pragma unroll
  for (int m = 0; m < 4; ++m) {
#pragma unroll
    for (int n = 0; n < 4; ++n) {
      int col = n0 + wc*64 + n*16 + r;
      float bv = bias[col];
      int r0 = m0 + wr*64 + m*16 + rq;
      if (OUT_MODE == 2) {
        ushort4 o;
        o.x = f2bf(acc[m][n][0] + bv); o.y = f2bf(acc[m][n][1] + bv);
        o.z = f2bf(acc[m][n][2] + bv); o.w = f2bf(acc[m][n][3] + bv);
        size_t addr = (size_t)((r0 >> 11) * 1024 + col) * SEQ + (r0 & 2047);
        *reinterpret_cast<ushort4*>(Cb + addr) = o;
      } else {
#pragma unroll
        for (int i = 0; i < 4; ++i) {
          float v = (acc[m][n][i] + bv) * scale;
          if (OUT_MODE == 0) Cb[(size_t)(r0 + i) * D_MODEL + col] = f2bf(v);
          else               Cf[(size_t)(r0 + i) * D_MODEL + col] = v;
        }
      }
    }
  }
}

// S*(1/sqrt(64))*log2(e) folded into Q
#define QSCALE (0.125f * 1.4426950408889634f)

__global__ __launch_bounds__(256)
void gemm_qkv(const unsigned short* __restrict__ xb,
              const unsigned short* __restrict__ Wqb,
              const unsigned short* __restrict__ Wkb,
              const unsigned short* __restrict__ Wvb,
              const float* __restrict__ bq, const float* __restrict__ bk,
              const float* __restrict__ bv,
              unsigned short* __restrict__ Qb, unsigned short* __restrict__ Kb,
              unsigned short* __restrict__ Vt)
{
  if (blockIdx.z == 0)      gemm_body<0>(xb, Wqb, bq, Qb, nullptr, QSCALE);
  else if (blockIdx.z == 1) gemm_body<0>(xb, Wkb, bk, Kb, nullptr, 1.0f);
  else                      gemm_body<2>(xb, Wvb, bv, Vt, nullptr, 1.0f);
}

__global__ __launch_bounds__(256)
void gemm_out(const unsigned short* __restrict__ Ab,
              const unsigned short* __restrict__ Wob,
              const float* __restrict__ bo, float* __restrict__ Cf)
{
  gemm_body<1>(Ab, Wob, bo, nullptr, Cf, 1.0f);
}

// ---------------- causal flash attention, swapped-operand in-register softmax ----
// grid (16, 64), qt descending. 4 waves x 32 q-rows, KVBLK=64, 32x32x16 MFMA.
// S^T = mfma(K, Q): lane owns q = lane&31; m/l per-lane scalars.
// PV swapped: O^T = mfma(V^T, P^T): acc keeps q = lane&31.
__global__ __launch_bounds__(256, 3)
void attn_fwd(const unsigned short* __restrict__ Qb,
              const unsigned short* __restrict__ Kb,
              const unsigned short* __restrict__ Vt,   // [b*1024+h*64+d][2048]
              unsigned short* __restrict__ Ab)
{
  __shared__ __align__(16) unsigned short Ks[2][64*64];  // [k][d] swizzled; epilogue: O[128][64]
  __shared__ __align__(16) unsigned short Vs[2][64*64];  // [d][k] swizzled
  const int tid  = threadIdx.x;
  const int lane = tid & 63;
  const int w    = tid >> 6;
  const int qt   = (int)gridDim.x - 1 - (int)blockIdx.x;
  const int bh   = blockIdx.y;
  const int b    = bh >> 4;
  const int h    = bh & 15;
  const size_t base = (size_t)b * SEQ;
  const int q0   = qt * 128;
  const int l31  = lane & 31;
  const int half = lane >> 5;
  const int aw   = q0 + w*32;              // wave's first q-row
  const int qg   = aw + l31;               // this lane's q-row
  const int nt   = (q0 + 127) >> 6;        // last KV tile index (= 2qt+1)
  const int xorK = (l31 & 7) << 3;         // read swizzle (row & 7)<<3, rows = *+l31
  const int scolS = (((lane & 7) ^ ((lane >> 3) & 7)) << 3);  // staging inverse swizzle
  const int srowS = lane >> 3;

  // Q fragments: qf[s] = Q[qg][16s + half*8 .. +8]  (pre-scaled by QSCALE)
  bf16x8 qf[4];
#pragma unroll
  for (int s = 0; s < 4; ++s)
    qf[s] = *reinterpret_cast<const bf16x8*>(
        Qb + (base + qg) * D_MODEL + h*DK + s*16 + half*8);

  f32x16 acc[2] = {};                      // O^T: acc[dg][g] -> d = dg*32+(g&3)+8*(g>>2)+4*half, q = l31
  float mrun = -INFINITY, lrun = 0.f;

  auto STAGE = [&](int buf, int t) {
#pragma unroll
    for (int p = 0; p < 2; ++p) {
      int c = w*2 + p;                     // chunk 0..7 (8 rows each)
      gload_lds16(Kb + (base + t*64 + c*8 + srowS) * D_MODEL + h*DK + scolS, &Ks[buf][c*512]);
      gload_lds16(Vt + ((size_t)(b*1024 + h*DK) + c*8 + srowS) * SEQ + t*64 + scolS, &Vs[buf][c*512]);
    }
  };

  STAGE(0, 0);
  __syncthreads();

  for (int t = 0; t <= nt; ++t) {
    const int cur = t & 1;
    if (t < nt) STAGE(cur ^ 1, t + 1);

    const bool dead = (t << 6) > aw + 31;
    if (!dead) {
      // ---- S^T = K Q^T : sacc[kg][g] = S[k = t*64+kg*32+(g&3)+8*(g>>2)+4*half][qg]
      f32x16 sacc[2] = {};
      __builtin_amdgcn_s_setprio(1);
#pragma unroll
      for (int kg = 0; kg < 2; ++kg)
#pragma unroll
        for (int s = 0; s < 4; ++s) {
          bf16x8 kf = *reinterpret_cast<const bf16x8*>(
              &Ks[cur][(kg*32 + l31)*64 + ((s*16 + half*8) ^ xorK)]);
          sacc[kg] = __builtin_amdgcn_mfma_f32_32x32x16_bf16(kf, qf[s], sacc[kg], 0, 0, 0);
        }
      __builtin_amdgcn_s_setprio(0);

      // ---- causal mask (diagonal-overlap tiles only; wave-uniform branch) ----
      if ((t << 6) + 63 > aw) {
        const int kbase = (t << 6) + half*4;
#pragma unroll
        for (int kg = 0; kg < 2; ++kg)
#pragma unroll
          for (int g = 0; g < 16; ++g) {
            int k = kbase + kg*32 + (g & 3) + ((g >> 2) << 3);
            if (k > qg) sacc[kg][g] = -INFINITY;
          }
      }

      // ---- row max: 31 in-lane fmax + one cross-half swap ----
      float tmax = sacc[0][0];
#pragma unroll
      for (int kg = 0; kg < 2; ++kg)
#pragma unroll
        for (int g = 0; g < 16; ++g) tmax = fmaxf(tmax, sacc[kg][g]);
      tmax = fmaxf(tmax, __shfl_xor(tmax, 32));

      // ---- defer-max (T13, log2 domain, THR=8) ----
      if (__any(tmax > mrun + 8.0f)) {
        float nm = fmaxf(mrun, tmax);
        float fs = exp2f(mrun - nm);
        mrun = nm; lrun *= fs;
#pragma unroll
        for (int dg = 0; dg < 2; ++dg)
#pragma unroll
          for (int g = 0; g < 16; ++g) acc[dg][g] *= fs;
      }

      // ---- P = exp2(S - m); pack to bf16 PV B-fragments via cvt_pk + permlane32_swap
      unsigned int pw[2][2][4];            // [kg][st][word]
#pragma unroll
      for (int kg = 0; kg < 2; ++kg) {
#pragma unroll
        for (int g = 0; g < 16; ++g) {
          float pv = exp2f(sacc[kg][g] - mrun);
          sacc[kg][g] = pv;
          lrun += pv;
        }
#pragma unroll
        for (int i = 0; i < 2; ++i) {
          unsigned int a, bb, c, d;
          asm("v_cvt_pk_bf16_f32 %0, %1, %2" : "=v"(a)  : "v"(sacc[kg][2*i]),    "v"(sacc[kg][2*i+1]));
          asm("v_cvt_pk_bf16_f32 %0, %1, %2" : "=v"(bb) : "v"(sacc[kg][4+2*i]),  "v"(sacc[kg][5+2*i]));
          asm("v_cvt_pk_bf16_f32 %0, %1, %2" : "=v"(c)  : "v"(sacc[kg][8+2*i]),  "v"(sacc[kg][9+2*i]));
          asm("v_cvt_pk_bf16_f32 %0, %1, %2" : "=v"(d)  : "v"(sacc[kg][12+2*i]), "v"(sacc[kg][13+2*i]));
          asm("v_permlane32_swap_b32 %0, %1" : "+v"(a), "+v"(bb));
          asm("v_permlane32_swap_b32 %0, %1" : "+v"(c), "+v"(d));
          pw[kg][0][i] = a; pw[kg][0][2+i] = bb;
          pw[kg][1][i] = c; pw[kg][1][2+i] = d;
        }
      }

      // ---- O^T += V^T P^T ----
      __builtin_amdgcn_s_setprio(1);
#pragma unroll
      for (int dg = 0; dg < 2; ++dg)
#pragma unroll
        for (int kg = 0; kg < 2; ++kg)
#pragma unroll
          for (int st = 0; st < 2; ++st) {
            int vrow = dg*32 + l31;
            int vcol = kg*32 + st*16 + half*8;
            bf16x8 vf = *reinterpret_cast<const bf16x8*>(
                &Vs[cur][vrow*64 + (vcol ^ xorK)]);
            bf16x8 pf = __builtin_bit_cast(bf16x8,
                u32x4{pw[kg][st][0], pw[kg][st][1], pw[kg][st][2], pw[kg][st][3]});
            acc[dg] = __builtin_amdgcn_mfma_f32_32x32x16_bf16(vf, pf, acc[dg], 0, 0, 0);
          }
      __builtin_amdgcn_s_setprio(0);
    }
    __syncthreads();
  }

  // ---- epilogue: transpose O^T -> O through retired K buffer, coalesced store --
  float ltot = lrun + __shfl_xor(lrun, 32);
  float rinv = 1.0f / ltot;
  unsigned short* Os = &Ks[0][0];          // 128 x 64 shorts = 16 KB
  const int qloc = w*32 + l31;
#pragma unroll
  for (int dg = 0; dg < 2; ++dg)
#pragma unroll
    for (int g = 0; g < 16; ++g) {
      int d = dg*32 + (g & 3) + ((g >> 2) << 3) + half*4;
      Os[qloc*64 + (d ^ ((qloc & 7) << 3))] = f2bf(acc[dg][g] * rinv);
    }
  __syncthreads();
  {
    const int q  = tid >> 1;
    const int c0 = (tid & 1) * 32;
#pragma unroll
    for (int u = 0; u < 4; ++u) {
      int c = c0 + u*8;
      bf16x8 vv = *reinterpret_cast<const bf16x8*>(&Os[q*64 + (c ^ ((q & 7) << 3))]);
      *reinterpret_cast<bf16x8*>(&Ab[(base + q0 + q) * D_MODEL + h*DK + c]) = vv;
    }
  }
}

// ---------------- launch ----------------
extern "C" void kernel_launch(void* const* d_in, const int* in_sizes, int n_in,
                              void* d_out, int out_size, void* d_ws, size_t ws_size,
                              hipStream_t stream) {
  const float* x  = (const float*)d_in[0];
  const float* Wq = (const float*)d_in[1];
  const float* bq = (const float*)d_in[2];
  const float* Wk = (const float*)d_in[3];
  const float* bk = (const float*)d_in[4];
  const float* Wv = (const float*)d_in[5];
  const float* bv = (const float*)d_in[6];
  const float* Wo = (const float*)d_in[7];
  const float* bo = (const float*)d_in[8];

  unsigned short* ws = (unsigned short*)d_ws;
  const size_t NX = (size_t)NROW * D_MODEL;
  const size_t NW = (size_t)D_MODEL * D_MODEL;
  unsigned short* xb  = ws;
  unsigned short* Wqb = xb  + NX;
  unsigned short* Wkb = Wqb + NW;
  unsigned short* Wvb = Wkb + NW;
  unsigned short* Wob = Wvb + NW;
  unsigned short* Qb  = Wob + NW;
  unsigned short* Kb  = Qb  + NX;
  unsigned short* Vt  = Kb  + NX;   // [b*1024 + h*64 + d][2048]
  unsigned short* Ab  = xb;         // reuse xb after projections

  cvt_bf16<<<dim3((unsigned)(NX/4/256)), 256, 0, stream>>>(x, xb, (int)(NX/4));
  cvt_bf16_w4<<<dim3((unsigned)(NW/4/256), 1, 4), 256, 0, stream>>>(
      Wq, Wk, Wv, Wo, Wqb, Wkb, Wvb, Wob, (int)(NW/4));

  gemm_qkv<<<dim3(NROW/128, D_MODEL/128, 3), 256, 0, stream>>>(
      xb, Wqb, Wkb, Wvb, bq, bk, bv, Qb, Kb, Vt);

  attn_fwd<<<dim3(SEQ/128, BATCH*N_HEADS), 256, 0, stream>>>(Qb, Kb, Vt, Ab);

  gemm_out<<<dim3(NROW/128, D_MODEL/128, 1), 256, 0, stream>>>(
      Ab, Wob, bo, (float*)d_out);
}

// Round 5
// 188.620 us; speedup vs baseline: 2.8435x; 1.2886x over previous
//
#include <hip/hip_runtime.h>
#include <hip/hip_bf16.h>

#define D_MODEL 1024
#define N_HEADS 16
#define DK      64
#define BATCH   4
#define SEQ     2048
#define NROW    (BATCH*SEQ)   // 8192

typedef __attribute__((ext_vector_type(8)))  short bf16x8;
typedef __attribute__((ext_vector_type(4)))  float f32x4;
typedef __attribute__((ext_vector_type(16))) float f32x16;
typedef __attribute__((ext_vector_type(4)))  unsigned int u32x4;

__device__ __forceinline__ unsigned short f2bf(float f) {
  unsigned int u = __float_as_uint(f);
  u += 0x7fff + ((u >> 16) & 1);          // round-to-nearest-even
  return (unsigned short)(u >> 16);
}

__device__ __forceinline__ void gload_lds16(const void* g, void* l) {
  __builtin_amdgcn_global_load_lds((const __attribute__((address_space(1))) void*)g,
                                   (__attribute__((address_space(3))) void*)l,
                                   16, 0, 0);
}

// ---------------- fp32 -> bf16 conversion ----------------
__global__ void cvt_bf16(const float* __restrict__ s, unsigned short* __restrict__ d, int n4) {
  int i = blockIdx.x * 256 + threadIdx.x;
  if (i >= n4) return;
  float4 f = reinterpret_cast<const float4*>(s)[i];
  ushort4 o;
  o.x = f2bf(f.x); o.y = f2bf(f.y); o.z = f2bf(f.z); o.w = f2bf(f.w);
  reinterpret_cast<ushort4*>(d)[i] = o;
}

__global__ void cvt_bf16_w4(const float* __restrict__ s0, const float* __restrict__ s1,
                            const float* __restrict__ s2, const float* __restrict__ s3,
                            unsigned short* __restrict__ d0, unsigned short* __restrict__ d1,
                            unsigned short* __restrict__ d2, unsigned short* __restrict__ d3,
                            int n4) {
  int i = blockIdx.x * 256 + threadIdx.x;
  if (i >= n4) return;
  const float* s = blockIdx.z == 0 ? s0 : blockIdx.z == 1 ? s1 : blockIdx.z == 2 ? s2 : s3;
  unsigned short* d = blockIdx.z == 0 ? d0 : blockIdx.z == 1 ? d1 : blockIdx.z == 2 ? d2 : d3;
  float4 f = reinterpret_cast<const float4*>(s)[i];
  ushort4 o;
  o.x = f2bf(f.x); o.y = f2bf(f.y); o.z = f2bf(f.z); o.w = f2bf(f.w);
  reinterpret_cast<ushort4*>(d)[i] = o;
}

// ---------------- GEMM: C[m][n] = (sum_k A[m][k]*W[n][k] + bias[n]) * scale --------
template<int OUT_MODE>   // 0 = bf16 natural; 1 = f32 natural; 2 = bf16 V-transposed
__device__ __forceinline__ void gemm_body(const unsigned short* __restrict__ A,
                                          const unsigned short* __restrict__ Bw,
                                          const float* __restrict__ bias,
                                          unsigned short* __restrict__ Cb,
                                          float* __restrict__ Cf, float scale)
{
  __shared__ __align__(16) unsigned short As[128*64];
  __shared__ __align__(16) unsigned short Bs[128*64];
  const int tid  = threadIdx.x;
  const int lane = tid & 63;
  const int w    = tid >> 6;
  const int wr   = w >> 1, wc = w & 1;
  const int m0   = blockIdx.x * 128;
  const int n0   = blockIdx.y * 128;
  const int r    = lane & 15;
  const int ko   = (lane >> 4) * 8;
  const int srow = lane >> 3;
  const int scol = (lane & 7) * 8;

  f32x4 acc[4][4] = {};

  for (int kt = 0; kt < D_MODEL; kt += 64) {
    __syncthreads();
#pragma unroll
    for (int p = 0; p < 4; ++p) {
      int c = w * 4 + p;
      gload_lds16(A  + (size_t)(m0 + c*8 + srow) * D_MODEL + kt + scol, As + c*512);
      gload_lds16(Bw + (size_t)(n0 + c*8 + srow) * D_MODEL + kt + scol, Bs + c*512);
    }
    __syncthreads();
#pragma unroll
    for (int ks = 0; ks < 2; ++ks) {
      bf16x8 af[4], bfr[4];
#pragma unroll
      for (int m = 0; m < 4; ++m)
        af[m]  = *reinterpret_cast<const bf16x8*>(As + (wr*64 + m*16 + r)*64 + ks*32 + ko);
#pragma unroll
      for (int n = 0; n < 4; ++n)
        bfr[n] = *reinterpret_cast<const bf16x8*>(Bs + (wc*64 + n*16 + r)*64 + ks*32 + ko);
#pragma unroll
      for (int m = 0; m < 4; ++m)
#pragma unroll
        for (int n = 0; n < 4; ++n)
          acc[m][n] = __builtin_amdgcn_mfma_f32_16x16x32_bf16(af[m], bfr[n], acc[m][n], 0, 0, 0);
    }
  }

  const int rq = (lane >> 4) * 4;
#pragma unroll
  for (int m = 0; m < 4; ++m) {
#pragma unroll
    for (int n = 0; n < 4; ++n) {
      int col = n0 + wc*64 + n*16 + r;
      float bv = bias[col];
      int r0 = m0 + wr*64 + m*16 + rq;
      if (OUT_MODE == 2) {
        ushort4 o;
        o.x = f2bf(acc[m][n][0] + bv); o.y = f2bf(acc[m][n][1] + bv);
        o.z = f2bf(acc[m][n][2] + bv); o.w = f2bf(acc[m][n][3] + bv);
        size_t addr = (size_t)((r0 >> 11) * 1024 + col) * SEQ + (r0 & 2047);
        *reinterpret_cast<ushort4*>(Cb + addr) = o;
      } else {
#pragma unroll
        for (int i = 0; i < 4; ++i) {
          float v = (acc[m][n][i] + bv) * scale;
          if (OUT_MODE == 0) Cb[(size_t)(r0 + i) * D_MODEL + col] = f2bf(v);
          else               Cf[(size_t)(r0 + i) * D_MODEL + col] = v;
        }
      }
    }
  }
}

// S*(1/sqrt(64))*log2(e) folded into Q
#define QSCALE (0.125f * 1.4426950408889634f)

__global__ __launch_bounds__(256)
void gemm_qkv(const unsigned short* __restrict__ xb,
              const unsigned short* __restrict__ Wqb,
              const unsigned short* __restrict__ Wkb,
              const unsigned short* __restrict__ Wvb,
              const float* __restrict__ bq, const float* __restrict__ bk,
              const float* __restrict__ bv,
              unsigned short* __restrict__ Qb, unsigned short* __restrict__ Kb,
              unsigned short* __restrict__ Vt)
{
  if (blockIdx.z == 0)      gemm_body<0>(xb, Wqb, bq, Qb, nullptr, QSCALE);
  else if (blockIdx.z == 1) gemm_body<0>(xb, Wkb, bk, Kb, nullptr, 1.0f);
  else                      gemm_body<2>(xb, Wvb, bv, Vt, nullptr, 1.0f);
}

__global__ __launch_bounds__(256)
void gemm_out(const unsigned short* __restrict__ Ab,
              const unsigned short* __restrict__ Wob,
              const float* __restrict__ bo, float* __restrict__ Cf)
{
  gemm_body<1>(Ab, Wob, bo, nullptr, Cf, 1.0f);
}

// ---------------- causal flash attention, swapped-operand in-register softmax ----
// flat grid 1024, XCD-swizzled: xcd = flat&7 owns 8 bh (4 MB K/V = one L2).
// 4 waves x 32 q-rows, KVBLK=64, 32x32x16 MFMA, S^T = mfma(K,Q), O^T = mfma(V^T,P^T).
// Counted-vmcnt double-buffer: tile t+1 loads stay in flight across tile t compute.
__global__ __launch_bounds__(256, 3)
void attn_fwd(const unsigned short* __restrict__ Qb,
              const unsigned short* __restrict__ Kb,
              const unsigned short* __restrict__ Vt,   // [b*1024+h*64+d][2048]
              unsigned short* __restrict__ Ab)
{
  __shared__ __align__(16) unsigned short Ks[2][64*64];  // [k][d] swizzled; epilogue: O[128][64]
  __shared__ __align__(16) unsigned short Vs[2][64*64];  // [d][k] swizzled
  const int tid  = threadIdx.x;
  const int lane = tid & 63;
  const int w    = tid >> 6;
  // XCD-aware remap: 1024 = 8 xcd * (8 bh * 16 qt)
  const int flat = blockIdx.x;
  const int xcd  = flat & 7;
  const int idx  = flat >> 3;
  const int bh   = xcd * 8 + (idx & 7);
  const int qt   = 15 - (idx >> 3);        // descending: long blocks first
  const int b    = bh >> 4;
  const int h    = bh & 15;
  const size_t base = (size_t)b * SEQ;
  const int q0   = qt * 128;
  const int l31  = lane & 31;
  const int half = lane >> 5;
  const int aw   = q0 + w*32;              // wave's first q-row
  const int qg   = aw + l31;               // this lane's q-row
  const int nt   = (q0 + 127) >> 6;        // last KV tile index (= 2qt+1)
  const int xorK = (l31 & 7) << 3;         // read swizzle, rows = *+l31
  const int scolS = (((lane & 7) ^ ((lane >> 3) & 7)) << 3);  // staging inverse swizzle
  const int srowS = lane >> 3;

  // Q fragments: qf[s] = Q[qg][16s + half*8 .. +8]  (pre-scaled by QSCALE)
  bf16x8 qf[4];
#pragma unroll
  for (int s = 0; s < 4; ++s)
    qf[s] = *reinterpret_cast<const bf16x8*>(
        Qb + (base + qg) * D_MODEL + h*DK + s*16 + half*8);

  f32x16 acc[2] = {};                      // O^T: d = dg*32+(g&3)+8*(g>>2)+4*half, q = l31
  float mrun = -INFINITY, lrun = 0.f;

  auto STAGE = [&](int buf, int t) {       // 4 gload_lds per wave
#pragma unroll
    for (int p = 0; p < 2; ++p) {
      int c = w*2 + p;                     // chunk 0..7 (8 rows each)
      gload_lds16(Kb + (base + t*64 + c*8 + srowS) * D_MODEL + h*DK + scolS, &Ks[buf][c*512]);
      gload_lds16(Vt + ((size_t)(b*1024 + h*DK) + c*8 + srowS) * SEQ + t*64 + scolS, &Vs[buf][c*512]);
    }
  };

  STAGE(0, 0);
  asm volatile("s_waitcnt vmcnt(0)" ::: "memory");  // drain Q loads + tile 0

  for (int t = 0; t <= nt; ++t) {
    const int cur = t & 1;
    if (t < nt) {
      STAGE(cur ^ 1, t + 1);               // issue next tile: stays in flight all iter
      asm volatile("s_waitcnt vmcnt(4)" ::: "memory");  // only tile-t loads drained
    } else {
      asm volatile("s_waitcnt vmcnt(0)" ::: "memory");
    }
    __builtin_amdgcn_s_barrier();          // all waves' tile-t chunks written
    __builtin_amdgcn_sched_barrier(0);

    const bool dead = (t << 6) > aw + 31;
    if (!dead) {
      // ---- S^T = K Q^T : sacc[kg][g] = S[k = t*64+kg*32+(g&3)+8*(g>>2)+4*half][qg]
      f32x16 sacc[2] = {};
      __builtin_amdgcn_s_setprio(1);
#pragma unroll
      for (int kg = 0; kg < 2; ++kg)
#pragma unroll
        for (int s = 0; s < 4; ++s) {
          bf16x8 kf = *reinterpret_cast<const bf16x8*>(
              &Ks[cur][(kg*32 + l31)*64 + ((s*16 + half*8) ^ xorK)]);
          sacc[kg] = __builtin_amdgcn_mfma_f32_32x32x16_bf16(kf, qf[s], sacc[kg], 0, 0, 0);
        }
      __builtin_amdgcn_s_setprio(0);

      // ---- causal mask (diagonal-overlap tiles only) ----
      if ((t << 6) + 63 > aw) {
        const int kbase = (t << 6) + half*4;
#pragma unroll
        for (int kg = 0; kg < 2; ++kg)
#pragma unroll
          for (int g = 0; g < 16; ++g) {
            int k = kbase + kg*32 + (g & 3) + ((g >> 2) << 3);
            if (k > qg) sacc[kg][g] = -INFINITY;
          }
      }

      // ---- row max: in-lane fmax chain + one cross-half swap ----
      float tmax = sacc[0][0];
#pragma unroll
      for (int kg = 0; kg < 2; ++kg)
#pragma unroll
        for (int g = 0; g < 16; ++g) tmax = fmaxf(tmax, sacc[kg][g]);
      tmax = fmaxf(tmax, __shfl_xor(tmax, 32));

      // ---- defer-max (T13, log2 domain, THR=8) ----
      if (__any(tmax > mrun + 8.0f)) {
        float nm = fmaxf(mrun, tmax);
        float fs = exp2f(mrun - nm);
        mrun = nm; lrun *= fs;
#pragma unroll
        for (int dg = 0; dg < 2; ++dg)
#pragma unroll
          for (int g = 0; g < 16; ++g) acc[dg][g] *= fs;
      }

      // ---- P = exp2(S - m); pack to PV B-fragments via cvt_pk + permlane32_swap --
      unsigned int pw[2][2][4];            // [kg][st][word]
#pragma unroll
      for (int kg = 0; kg < 2; ++kg) {
#pragma unroll
        for (int g = 0; g < 16; ++g) {
          float pv = exp2f(sacc[kg][g] - mrun);
          sacc[kg][g] = pv;
          lrun += pv;
        }
#pragma unroll
        for (int i = 0; i < 2; ++i) {
          unsigned int a, bb, c, d;
          asm("v_cvt_pk_bf16_f32 %0, %1, %2" : "=v"(a)  : "v"(sacc[kg][2*i]),    "v"(sacc[kg][2*i+1]));
          asm("v_cvt_pk_bf16_f32 %0, %1, %2" : "=v"(bb) : "v"(sacc[kg][4+2*i]),  "v"(sacc[kg][5+2*i]));
          asm("v_cvt_pk_bf16_f32 %0, %1, %2" : "=v"(c)  : "v"(sacc[kg][8+2*i]),  "v"(sacc[kg][9+2*i]));
          asm("v_cvt_pk_bf16_f32 %0, %1, %2" : "=v"(d)  : "v"(sacc[kg][12+2*i]), "v"(sacc[kg][13+2*i]));
          asm("v_permlane32_swap_b32 %0, %1" : "+v"(a), "+v"(bb));
          asm("v_permlane32_swap_b32 %0, %1" : "+v"(c), "+v"(d));
          pw[kg][0][i] = a; pw[kg][0][2+i] = bb;
          pw[kg][1][i] = c; pw[kg][1][2+i] = d;
        }
      }

      // ---- O^T += V^T P^T ----
      __builtin_amdgcn_s_setprio(1);
#pragma unroll
      for (int dg = 0; dg < 2; ++dg)
#pragma unroll
        for (int kg = 0; kg < 2; ++kg)
#pragma unroll
          for (int st = 0; st < 2; ++st) {
            int vrow = dg*32 + l31;
            int vcol = kg*32 + st*16 + half*8;
            bf16x8 vf = *reinterpret_cast<const bf16x8*>(
                &Vs[cur][vrow*64 + (vcol ^ xorK)]);
            bf16x8 pf = __builtin_bit_cast(bf16x8,
                u32x4{pw[kg][st][0], pw[kg][st][1], pw[kg][st][2], pw[kg][st][3]});
            acc[dg] = __builtin_amdgcn_mfma_f32_32x32x16_bf16(vf, pf, acc[dg], 0, 0, 0);
          }
      __builtin_amdgcn_s_setprio(0);
    }
    __builtin_amdgcn_s_barrier();          // buf cur free for overwrite next iter
  }

  // ---- epilogue: transpose O^T -> O through retired K buffer, coalesced store --
  float ltot = lrun + __shfl_xor(lrun, 32);
  float rinv = 1.0f / ltot;
  unsigned short* Os = &Ks[0][0];          // 128 x 64 shorts = 16 KB
  const int qloc = w*32 + l31;
#pragma unroll
  for (int dg = 0; dg < 2; ++dg)
#pragma unroll
    for (int g = 0; g < 16; ++g) {
      int d = dg*32 + (g & 3) + ((g >> 2) << 3) + half*4;
      Os[qloc*64 + (d ^ ((qloc & 7) << 3))] = f2bf(acc[dg][g] * rinv);
    }
  __syncthreads();
  {
    const int q  = tid >> 1;
    const int c0 = (tid & 1) * 32;
#pragma unroll
    for (int u = 0; u < 4; ++u) {
      int c = c0 + u*8;
      bf16x8 vv = *reinterpret_cast<const bf16x8*>(&Os[q*64 + (c ^ ((q & 7) << 3))]);
      *reinterpret_cast<bf16x8*>(&Ab[(base + q0 + q) * D_MODEL + h*DK + c]) = vv;
    }
  }
}

// ---------------- launch ----------------
extern "C" void kernel_launch(void* const* d_in, const int* in_sizes, int n_in,
                              void* d_out, int out_size, void* d_ws, size_t ws_size,
                              hipStream_t stream) {
  const float* x  = (const float*)d_in[0];
  const float* Wq = (const float*)d_in[1];
  const float* bq = (const float*)d_in[2];
  const float* Wk = (const float*)d_in[3];
  const float* bk = (const float*)d_in[4];
  const float* Wv = (const float*)d_in[5];
  const float* bv = (const float*)d_in[6];
  const float* Wo = (const float*)d_in[7];
  const float* bo = (const float*)d_in[8];

  unsigned short* ws = (unsigned short*)d_ws;
  const size_t NX = (size_t)NROW * D_MODEL;
  const size_t NW = (size_t)D_MODEL * D_MODEL;
  unsigned short* xb  = ws;
  unsigned short* Wqb = xb  + NX;
  unsigned short* Wkb = Wqb + NW;
  unsigned short* Wvb = Wkb + NW;
  unsigned short* Wob = Wvb + NW;
  unsigned short* Qb  = Wob + NW;
  unsigned short* Kb  = Qb  + NX;
  unsigned short* Vt  = Kb  + NX;   // [b*1024 + h*64 + d][2048]
  unsigned short* Ab  = xb;         // reuse xb after projections

  cvt_bf16<<<dim3((unsigned)(NX/4/256)), 256, 0, stream>>>(x, xb, (int)(NX/4));
  cvt_bf16_w4<<<dim3((unsigned)(NW/4/256), 1, 4), 256, 0, stream>>>(
      Wq, Wk, Wv, Wo, Wqb, Wkb, Wvb, Wob, (int)(NW/4));

  gemm_qkv<<<dim3(NROW/128, D_MODEL/128, 3), 256, 0, stream>>>(
      xb, Wqb, Wkb, Wvb, bq, bk, bv, Qb, Kb, Vt);

  attn_fwd<<<dim3(1024), 256, 0, stream>>>(Qb, Kb, Vt, Ab);

  gemm_out<<<dim3(NROW/128, D_MODEL/128, 1), 256, 0, stream>>>(
      Ab, Wob, bo, (float*)d_out);
}